// Round 1
// baseline (109.844 us; speedup 1.0000x reference)
//
#include <hip/hip_runtime.h>

// CTC batch cost (keras ctc_batch_cost semantics), B=256 T=512 C=256 L=64.
// One block per batch element; thread s owns extended state s (S=129).
// Log2-domain forward DP, alpha double-buffered in LDS, 1 barrier/step,
// 8-deep register prefetch of gathered y_pred values.

constexpr int Bc = 256;
constexpr int Tc = 512;
constexpr int Cc = 256;
constexpr int Lc = 64;
constexpr int Sc = 2 * Lc + 1;   // 129
constexpr int PF = 8;            // prefetch depth (steps)

#define NEGF (-1e30f)
#define EPSF (1e-7f)

__device__ __forceinline__ float flog2(float x) {
    float r; asm("v_log_f32 %0, %1" : "=v"(r) : "v"(x)); return r;
}
__device__ __forceinline__ float fexp2(float x) {
    float r; asm("v_exp_f32 %0, %1" : "=v"(r) : "v"(x)); return r;
}

__global__ __launch_bounds__(192, 1) void ctc_loss_kernel(
        const int* __restrict__ y_true,
        const float* __restrict__ y_pred,
        float* __restrict__ out)
{
    const int b = blockIdx.x;
    const int tid = threadIdx.x;

    __shared__ int   lab[Lc];
    __shared__ float A[Sc + 2];   // states at [s+2]; [0..1] = NEG padding
    __shared__ float Bb[Sc + 2];

    if (tid < Lc) lab[tid] = y_true[b * Lc + tid];
    if (tid < 2) { A[tid] = NEGF; Bb[tid] = NEGF; }
    __syncthreads();

    const int s = tid;
    const bool active = (s < Sc);

    // t-invariant per-state setup: channel to gather, skip-transition mask.
    int ch = Cc - 1;              // blank for even states
    bool allow = false;
    if (active && (s & 1)) {
        const int k = s >> 1;
        ch = lab[k];
        if (s >= 3) allow = (lab[k] != lab[k - 1]);
    }
    const float* __restrict__ row = y_pred + (size_t)b * Tc * Cc + ch;

    // t = 0 init: only s<2 reachable.
    float myA = NEGF;
    if (active) {
        const float lp0 = flog2(row[0] + EPSF);
        myA = (s < 2) ? lp0 : NEGF;
        A[s + 2] = myA;
    }
    __syncthreads();

    // Prefetch steps t = 1..PF.
    float g[PF];
    #pragma unroll
    for (int i = 0; i < PF; ++i) {
        const int t = 1 + i;
        g[i] = (active && t < Tc) ? row[(size_t)t * Cc] : 1.f;
    }

    for (int tb = 1; tb < Tc; tb += PF) {
        // Issue next chunk's loads before computing this chunk (latency hide).
        float n[PF];
        #pragma unroll
        for (int i = 0; i < PF; ++i) {
            const int t = tb + PF + i;
            n[i] = (active && t < Tc) ? row[(size_t)t * Cc] : 1.f;
        }
        #pragma unroll
        for (int i = 0; i < PF; ++i) {
            const int t = tb + i;
            if (t < Tc) {                      // block-uniform guard
                // parity: tb odd, so i even <=> t odd <=> read A, write Bb
                float* __restrict__ rd = (i & 1) ? Bb : A;
                float* __restrict__ wr = (i & 1) ? A  : Bb;
                if (active) {
                    const float a1 = rd[s + 1];                 // alpha[s-1]
                    const float a2 = allow ? rd[s] : NEGF;      // alpha[s-2]
                    const float lp = flog2(g[i] + EPSF);
                    const float m  = fmaxf(myA, fmaxf(a1, a2));
                    const float sum = fexp2(myA - m) + fexp2(a1 - m) + fexp2(a2 - m);
                    myA = m + flog2(sum) + lp;
                    wr[s + 2] = myA;
                }
                __syncthreads();
            }
        }
        #pragma unroll
        for (int i = 0; i < PF; ++i) g[i] = n[i];
    }

    // Last step is t=511 (odd) -> final alpha lives in Bb.
    if (tid == 0) {
        const float x = Bb[Sc + 1];   // alphaT[S-1] (s=128)
        const float y = Bb[Sc];       // alphaT[S-2] (s=127)
        const float m = fmaxf(x, y);
        const float l2 = m + flog2(fexp2(x - m) + fexp2(y - m));
        out[b] = -0.69314718055994530942f * l2;   // ln2 * log2 -> natural log
    }
}

extern "C" void kernel_launch(void* const* d_in, const int* in_sizes, int n_in,
                              void* d_out, int out_size, void* d_ws, size_t ws_size,
                              hipStream_t stream) {
    const int*   y_true = (const int*)d_in[0];
    const float* y_pred = (const float*)d_in[1];
    float*       out    = (float*)d_out;
    ctc_loss_kernel<<<dim3(Bc), dim3(192), 0, stream>>>(y_true, y_pred, out);
}

// Round 2
// 39.121 us; speedup vs baseline: 2.8078x; 2.8078x over previous
//
#include <hip/hip_runtime.h>

// CTC batch cost, B=256 T=512 C=256 L=64 (S=129).
// One block per batch element, 2 waves: wave0 = forward DP over t=0..255,
// wave1 = backward DP over t=511..256. Lane l owns states {2l, 2l+1};
// lane 63 also owns state 128. Cross-state comm via __shfl (no barriers);
// single __syncthreads to combine at the cut. Log2-domain throughout.

constexpr int Bc = 256;
constexpr int Tc = 512;
constexpr int Cc = 256;
constexpr int Lc = 64;
constexpr int TCUT = 256;   // fwd covers t<TCUT, bwd covers t>=TCUT
constexpr int PF = 8;       // prefetch depth (steps)

#define NEGF (-1e30f)
#define EPSF (1e-7f)

__device__ __forceinline__ float flog2(float x) {
    float r; asm("v_log_f32 %0, %1" : "=v"(r) : "v"(x)); return r;
}
__device__ __forceinline__ float fexp2(float x) {
    float r; asm("v_exp_f32 %0, %1" : "=v"(r) : "v"(x)); return r;
}
// log2(2^a + 2^b), NEG-safe
__device__ __forceinline__ float lse2(float a, float b) {
    float m = fmaxf(a, b);
    float d = fminf(a, b) - m;          // <= 0
    return m + flog2(1.f + fexp2(d));
}
// log2(2^a + 2^b + 2^c), NEG-safe
__device__ __forceinline__ float lse3(float a, float b, float c) {
    float m = fmaxf(fmaxf(a, b), c);
    return m + flog2(fexp2(a - m) + fexp2(b - m) + fexp2(c - m));
}

__global__ __launch_bounds__(128, 1) void ctc_fb_kernel(
        const int* __restrict__ y_true,
        const float* __restrict__ y_pred,
        float* __restrict__ out)
{
    const int b    = blockIdx.x;
    const int lane = threadIdx.x & 63;
    const int wid  = threadIdx.x >> 6;

    __shared__ float Cl[64], Ch[64], Cex;

    const float* __restrict__ base = y_pred + (size_t)b * Tc * Cc;
    const int lab  = y_true[b * Lc + lane];      // label for state 2*lane+1
    const int labp = __shfl_up(lab, 1);          // lab[l-1]
    const int labn = __shfl_down(lab, 1);        // lab[l+1]

    float A_lo = NEGF, A_hi = NEGF, A_ex = NEGF;

    if (wid == 0) {
        // ---------- forward: t = 0 .. TCUT-1 ----------
        const bool allowF = (lane >= 1) && (lab != labp);
        float lo, hi, ex = NEGF;
        {
            const float lpB = flog2(base[255] + EPSF);
            const float lpL = flog2(base[lab] + EPSF);
            lo = (lane == 0) ? lpB : NEGF;   // state 0
            hi = (lane == 0) ? lpL : NEGF;   // state 1
        }
        float gB[PF], gL[PF];
        #pragma unroll
        for (int i = 0; i < PF; ++i) {
            const int t = 1 + i;
            gB[i] = base[(size_t)t * Cc + 255];
            gL[i] = base[(size_t)t * Cc + lab];
        }
        for (int tb = 1; tb < TCUT; tb += PF) {
            float nB[PF], nL[PF];
            #pragma unroll
            for (int i = 0; i < PF; ++i) {
                int t = tb + PF + i; t = (t > TCUT - 1) ? (TCUT - 1) : t;
                nB[i] = base[(size_t)t * Cc + 255];
                nL[i] = base[(size_t)t * Cc + lab];
            }
            #pragma unroll
            for (int i = 0; i < PF; ++i) {
                const int t = tb + i;
                if (t < TCUT) {
                    float prevHi = __shfl_up(hi, 1);
                    prevHi = (lane == 0) ? NEGF : prevHi;
                    const float lpB = flog2(gB[i] + EPSF);
                    const float lpL = flog2(gL[i] + EPSF);
                    const float oLo = lo, oHi = hi, oEx = ex;
                    ex = lse2(oEx, oHi) + lpB;                              // state 128 (lane63)
                    hi = lse3(oHi, oLo, allowF ? prevHi : NEGF) + lpL;      // state 2l+1
                    lo = lse2(oLo, prevHi) + lpB;                           // state 2l
                }
            }
            #pragma unroll
            for (int i = 0; i < PF; ++i) { gB[i] = nB[i]; gL[i] = nL[i]; }
        }
        A_lo = lo; A_hi = hi; A_ex = ex;
    } else {
        // ---------- backward: t = Tc-1 .. TCUT ----------
        const bool allowB = (lane < 63) && (labn != lab);
        float lo, hi, ex;
        {
            const int t = Tc - 1;
            const float lpB = flog2(base[(size_t)t * Cc + 255] + EPSF);
            const float lpL = flog2(base[(size_t)t * Cc + lab] + EPSF);
            lo = NEGF;
            hi = (lane == 63) ? lpL : NEGF;   // state 127
            ex = lpB;                          // state 128
        }
        float gB[PF], gL[PF];
        #pragma unroll
        for (int i = 0; i < PF; ++i) {
            const int t = Tc - 2 - i;
            gB[i] = base[(size_t)t * Cc + 255];
            gL[i] = base[(size_t)t * Cc + lab];
        }
        for (int tb = Tc - 2; tb >= TCUT; tb -= PF) {
            float nB[PF], nL[PF];
            #pragma unroll
            for (int i = 0; i < PF; ++i) {
                int t = tb - PF - i; t = (t < TCUT) ? TCUT : t;
                nB[i] = base[(size_t)t * Cc + 255];
                nL[i] = base[(size_t)t * Cc + lab];
            }
            #pragma unroll
            for (int i = 0; i < PF; ++i) {
                const int t = tb - i;
                if (t >= TCUT) {
                    float nlo = __shfl_down(lo, 1);
                    float nhi = __shfl_down(hi, 1);
                    nlo = (lane == 63) ? ex : nlo;      // B(2l+2); lane63: state 128
                    nhi = (lane == 63) ? NEGF : nhi;    // B(2l+3); lane63: none
                    const float lpB = flog2(gB[i] + EPSF);
                    const float lpL = flog2(gL[i] + EPSF);
                    const float oLo = lo, oHi = hi;
                    lo = lse2(oLo, oHi) + lpB;                               // state 2l
                    hi = lse3(oHi, nlo, allowB ? nhi : NEGF) + lpL;          // state 2l+1
                    ex = ex + lpB;                                           // state 128
                }
            }
            #pragma unroll
            for (int i = 0; i < PF; ++i) { gB[i] = nB[i]; gL[i] = nL[i]; }
        }
        // combine half-step (transition only, no emission): C from B_{TCUT}
        float nlo = __shfl_down(lo, 1);
        float nhi = __shfl_down(hi, 1);
        nlo = (lane == 63) ? ex : nlo;
        nhi = (lane == 63) ? NEGF : nhi;
        Cl[lane] = lse2(lo, hi);
        Ch[lane] = lse3(hi, nlo, allowB ? nhi : NEGF);
        if (lane == 63) Cex = ex;
    }

    __syncthreads();

    if (wid == 0) {
        float v = lse2(A_lo + Cl[lane], A_hi + Ch[lane]);
        if (lane == 63) v = lse2(v, A_ex + Cex);
        #pragma unroll
        for (int off = 32; off; off >>= 1) {
            const float o = __shfl_xor(v, off);
            v = lse2(v, o);
        }
        if (lane == 0) out[b] = -0.69314718055994530942f * v;  // ln2 * log2 -> ln
    }
}

extern "C" void kernel_launch(void* const* d_in, const int* in_sizes, int n_in,
                              void* d_out, int out_size, void* d_ws, size_t ws_size,
                              hipStream_t stream) {
    const int*   y_true = (const int*)d_in[0];
    const float* y_pred = (const float*)d_in[1];
    float*       out    = (float*)d_out;
    ctc_fb_kernel<<<dim3(Bc), dim3(128), 0, stream>>>(y_true, y_pred, out);
}

// Round 3
// 37.348 us; speedup vs baseline: 2.9411x; 1.0475x over previous
//
#include <hip/hip_runtime.h>

// CTC batch cost, B=256 T=512 C=256 L=64 (S=129).
// One block/batch, 2 waves: wave0 = forward DP t=0..255, wave1 = backward DP
// t=511..256, combined at the cut through LDS. Lane l owns states {2l,2l+1};
// state 128 carried as 'ex'. Log2-domain. Cross-lane via DPP wave shifts
// (no LDS in the chain). Blank-channel logs batched: one 64-lane gather +
// one vector log2 per 64 timesteps, per-step v_readlane.

constexpr int Bc = 256;
constexpr int Tc = 512;
constexpr int Cc = 256;
constexpr int Lc = 64;

#define NEGF (-1e30f)
#define EPSF (1e-7f)

__device__ __forceinline__ float flog2(float x) {
    float r; asm("v_log_f32 %0, %1" : "=v"(r) : "v"(x)); return r;
}
__device__ __forceinline__ float fexp2(float x) {
    float r; asm("v_exp_f32 %0, %1" : "=v"(r) : "v"(x)); return r;
}
// log2(2^a + 2^b), NEG-safe
__device__ __forceinline__ float lse2(float a, float b) {
    float m = fmaxf(a, b);
    float d = fminf(a, b) - m;
    return m + flog2(1.f + fexp2(d));
}
// log2(2^a + 2^b + 2^c), NEG-safe
__device__ __forceinline__ float lse3(float a, float b, float c) {
    float m = fmaxf(fmaxf(a, b), c);
    return m + flog2(fexp2(a - m) + fexp2(b - m) + fexp2(c - m));
}
// lane i <- lane i-1; lane 0 <- old   (DPP wave_shr:1)
__device__ __forceinline__ float dpp_up1(float old, float src) {
    return __int_as_float(__builtin_amdgcn_update_dpp(
        __float_as_int(old), __float_as_int(src), 0x138, 0xF, 0xF, false));
}
// lane i <- lane i+1; lane 63 <- old  (DPP wave_shl:1)
__device__ __forceinline__ float dpp_dn1(float old, float src) {
    return __int_as_float(__builtin_amdgcn_update_dpp(
        __float_as_int(old), __float_as_int(src), 0x130, 0xF, 0xF, false));
}
__device__ __forceinline__ float rdlane(float v, int idx) {
    return __int_as_float(__builtin_amdgcn_readlane(__float_as_int(v), idx));
}

__global__ __launch_bounds__(128, 1) void ctc_fb_kernel(
        const int* __restrict__ y_true,
        const float* __restrict__ y_pred,
        float* __restrict__ out)
{
    const int b    = blockIdx.x;
    const int lane = threadIdx.x & 63;
    const int wid  = threadIdx.x >> 6;

    __shared__ float Cl[64], Ch[64], Cex;

    const float* __restrict__ base = y_pred + (size_t)b * Tc * Cc;

    // Blank-channel gathers (address independent of labels; issue first).
    // Wave0 covers t=0..255 (blocks 0..3), wave1 covers t=256..511.
    const int tB0 = wid ? 256 : 0;
    const float bv0 = base[(size_t)(tB0 +       lane) * Cc + (Cc - 1)];
    const float bv1 = base[(size_t)(tB0 +  64 + lane) * Cc + (Cc - 1)];
    const float bv2 = base[(size_t)(tB0 + 128 + lane) * Cc + (Cc - 1)];
    const float bv3 = base[(size_t)(tB0 + 192 + lane) * Cc + (Cc - 1)];

    const int lab  = y_true[b * Lc + lane];      // label for state 2*lane+1
    const int labp = __shfl_up(lab, 1);
    const int labn = __shfl_down(lab, 1);
    const float* __restrict__ rowL = base + lab;

    float A_lo = NEGF, A_hi = NEGF, A_ex = NEGF;

    if (wid == 0) {
        // ---------------- forward: t = 0 .. 255 ----------------
        const bool allow = (lane >= 1) && (lab != labp);
        float p[15], g[16];
        #pragma unroll
        for (int i = 0; i < 15; ++i) p[i] = rowL[(size_t)(1 + i) * Cc];
        #pragma unroll
        for (int i = 0; i < 16; ++i) g[i] = rowL[(size_t)(16 + i) * Cc];
        const float lpBv0 = flog2(bv0 + EPSF), lpBv1 = flog2(bv1 + EPSF);
        const float lpBv2 = flog2(bv2 + EPSF), lpBv3 = flog2(bv3 + EPSF);

        float lo, hi, ex = NEGF;
        {   // t = 0 init: only states 0,1 reachable (lane 0)
            const float lpB = rdlane(lpBv0, 0);
            const float lpL = flog2(rowL[0] + EPSF);
            lo = (lane == 0) ? lpB : NEGF;
            hi = (lane == 0) ? lpL : NEGF;
        }
        // prologue t = 1..15 (blank block 0)
        #pragma unroll
        for (int i = 0; i < 15; ++i) {
            const float lpB = rdlane(lpBv0, 1 + i);
            const float prevHi = dpp_up1(NEGF, hi);
            const float lpL = flog2(p[i] + EPSF);
            const float nex = lse2(ex, hi) + lpB;
            const float nhi = lse3(hi, lo, allow ? prevHi : NEGF) + lpL;
            const float nlo = lse2(lo, prevHi) + lpB;
            ex = nex; hi = nhi; lo = nlo;
        }
        // 64-aligned-block-safe chunks: tb = 16,32,...,240
        for (int tb = 16; tb < 256; tb += 16) {
            float n[16];
            #pragma unroll
            for (int i = 0; i < 16; ++i) {
                int t = tb + 16 + i; t = t > 255 ? 255 : t;
                n[i] = rowL[(size_t)t * Cc];
            }
            const int blk = tb >> 6;
            float lpBv = lpBv0;
            lpBv = (blk == 1) ? lpBv1 : lpBv;
            lpBv = (blk == 2) ? lpBv2 : lpBv;
            lpBv = (blk == 3) ? lpBv3 : lpBv;
            const int ib = tb & 63;
            #pragma unroll
            for (int i = 0; i < 16; ++i) {
                const float lpB = rdlane(lpBv, ib + i);
                const float prevHi = dpp_up1(NEGF, hi);
                const float lpL = flog2(g[i] + EPSF);
                const float nex = lse2(ex, hi) + lpB;
                const float nhi = lse3(hi, lo, allow ? prevHi : NEGF) + lpL;
                const float nlo = lse2(lo, prevHi) + lpB;
                ex = nex; hi = nhi; lo = nlo;
            }
            #pragma unroll
            for (int i = 0; i < 16; ++i) g[i] = n[i];
        }
        A_lo = lo; A_hi = hi; A_ex = ex;
    } else {
        // ---------------- backward: t = 511 .. 256 ----------------
        const bool allow = (lane < 63) && (labn != lab);
        float p[15], g[16];
        #pragma unroll
        for (int i = 0; i < 15; ++i) p[i] = rowL[(size_t)(510 - i) * Cc];
        #pragma unroll
        for (int i = 0; i < 16; ++i) g[i] = rowL[(size_t)(495 - i) * Cc];
        const float lpBv0 = flog2(bv0 + EPSF), lpBv1 = flog2(bv1 + EPSF);
        const float lpBv2 = flog2(bv2 + EPSF), lpBv3 = flog2(bv3 + EPSF);

        float lo = NEGF, hi, ex;
        {   // t = 511 init (blank block 3 of this wave, idx 63)
            const float lpB = rdlane(lpBv3, 63);
            const float lpL = flog2(rowL[(size_t)511 * Cc] + EPSF);
            hi = (lane == 63) ? lpL : NEGF;   // state 127
            ex = lpB;                          // state 128
        }
        // prologue t = 510..496 (block 3; idx = t-448 = 62-i)
        #pragma unroll
        for (int i = 0; i < 15; ++i) {
            const float lpB = rdlane(lpBv3, 62 - i);
            const float nlo_s = dpp_dn1(ex, lo);     // B(2l+2); lane63 <- ex
            const float nhi_s = dpp_dn1(NEGF, hi);   // B(2l+3); lane63 <- NEG
            const float lpL = flog2(p[i] + EPSF);
            const float l2 = lse2(lo, hi) + lpB;
            const float h2 = lse3(hi, nlo_s, allow ? nhi_s : NEGF) + lpL;
            ex = ex + lpB;
            lo = l2; hi = h2;
        }
        // chunks tb = 495,479,...,271; step t = tb-i
        for (int tb = 495; tb >= 271; tb -= 16) {
            float n[16];
            #pragma unroll
            for (int i = 0; i < 16; ++i) {
                int t = tb - 16 - i; t = t < 256 ? 256 : t;
                n[i] = rowL[(size_t)t * Cc];
            }
            const int j = (tb >> 6) - 4;   // 3..0
            float lpBv = lpBv0;
            lpBv = (j == 1) ? lpBv1 : lpBv;
            lpBv = (j == 2) ? lpBv2 : lpBv;
            lpBv = (j == 3) ? lpBv3 : lpBv;
            const int ib = tb & 63;
            #pragma unroll
            for (int i = 0; i < 16; ++i) {
                const float lpB = rdlane(lpBv, ib - i);
                const float nlo_s = dpp_dn1(ex, lo);
                const float nhi_s = dpp_dn1(NEGF, hi);
                const float lpL = flog2(g[i] + EPSF);
                const float l2 = lse2(lo, hi) + lpB;
                const float h2 = lse3(hi, nlo_s, allow ? nhi_s : NEGF) + lpL;
                ex = ex + lpB;
                lo = l2; hi = h2;
            }
            #pragma unroll
            for (int i = 0; i < 16; ++i) g[i] = n[i];
        }
        // combine half-step at the cut (transition only, no emission)
        const float nlo_s = dpp_dn1(ex, lo);
        const float nhi_s = dpp_dn1(NEGF, hi);
        Cl[lane] = lse2(lo, hi);
        Ch[lane] = lse3(hi, nlo_s, allow ? nhi_s : NEGF);
        if (lane == 63) Cex = ex;
    }

    __syncthreads();

    if (wid == 0) {
        float v = lse2(A_lo + Cl[lane], A_hi + Ch[lane]);
        if (lane == 63) v = lse2(v, A_ex + Cex);
        #pragma unroll
        for (int off = 32; off; off >>= 1) v = lse2(v, __shfl_xor(v, off));
        if (lane == 0) out[b] = -0.69314718055994530942f * v;  // ln2*log2 -> ln
    }
}

extern "C" void kernel_launch(void* const* d_in, const int* in_sizes, int n_in,
                              void* d_out, int out_size, void* d_ws, size_t ws_size,
                              hipStream_t stream) {
    const int*   y_true = (const int*)d_in[0];
    const float* y_pred = (const float*)d_in[1];
    float*       out    = (float*)d_out;
    ctc_fb_kernel<<<dim3(Bc), dim3(128), 0, stream>>>(y_true, y_pred, out);
}